// Round 1
// baseline (280.782 us; speedup 1.0000x reference)
//
#include <hip/hip_runtime.h>
#include <math.h>

// Problem: x (B=2, C=64, T=16, H=128, W=128) fp32; w (1,2,7,7,7) fp32.
// out = sigmoid(conv3d(concat[max_c(x), mean_c(x)], w, pad=3)) * x
//
// Sizes (all powers of 2): per-b pooled = 16*128*128 = 262144 = 2^18 floats;
// per-(b,c) slice = 2^18; per-b x slice = 2^24; total x = 2^25 floats.

#define NP (2 * 16 * 128 * 128) // 524288 pooled points per channel

// ---------------- Kernel 1: channel max + mean pool (float4) ----------------
__global__ __launch_bounds__(256) void pool_kernel(const float* __restrict__ x,
                                                   float* __restrict__ pmax,
                                                   float* __restrict__ pavg) {
    int j = blockIdx.x * 256 + threadIdx.x; // float4 index in pooled space, [0, 131072)
    int b = j >> 16;                        // 65536 float4 per batch in pooled space
    int rest = j & 65535;
    const float4* x4 = (const float4*)x;
    int base = (b << 22) | rest;            // float4 index into x for c=0

    float4 v = x4[base];
    float4 vmax = v;
    float4 vsum = v;
#pragma unroll 8
    for (int c = 1; c < 64; ++c) {
        float4 u = x4[base + (c << 16)];
        vmax.x = fmaxf(vmax.x, u.x);
        vmax.y = fmaxf(vmax.y, u.y);
        vmax.z = fmaxf(vmax.z, u.z);
        vmax.w = fmaxf(vmax.w, u.w);
        vsum.x += u.x; vsum.y += u.y; vsum.z += u.z; vsum.w += u.w;
    }
    const float s = 1.0f / 64.0f;
    float4 vavg; vavg.x = vsum.x * s; vavg.y = vsum.y * s; vavg.z = vsum.z * s; vavg.w = vsum.w * s;
    ((float4*)pmax)[j] = vmax;
    ((float4*)pavg)[j] = vavg;
}

// ---------------- Kernel 2: 7x7x7 conv (2ch) + sigmoid -> attn ----------------
// Block = 256 threads handles one (b, t) and a 32x32 (h,w) tile.
// LDS stages one dz-plane of the 2-channel pooled halo: 2 x 38 x 38 (stride 39).
__global__ __launch_bounds__(256) void conv_kernel(const float* __restrict__ pooled, // pmax | pavg contiguous
                                                   const float* __restrict__ wgt,    // (1,2,7,7,7)
                                                   float* __restrict__ attn) {
    __shared__ float sm[2 * 38 * 39]; // 11856 B

    int bid = blockIdx.x;
    int tw0 = (bid & 3) << 5;
    int th0 = ((bid >> 2) & 3) << 5;
    int t = (bid >> 4) & 15;
    int b = bid >> 8;

    int tid = threadIdx.x;
    int ty = tid >> 3;         // 0..31 output row within tile
    int txg = (tid & 7) << 2;  // 0,4,...,28 output col group (4 consecutive w)

    float acc0 = 0.f, acc1 = 0.f, acc2 = 0.f, acc3 = 0.f;

    for (int dz = 0; dz < 7; ++dz) {
        int tsrc = t + dz - 3;
        if (tsrc < 0 || tsrc >= 16) continue; // block-uniform: t,dz uniform -> barriers stay uniform

        __syncthreads(); // protect LDS from previous plane's readers
        for (int i = tid; i < 2 * 38 * 38; i += 256) {
            int ch = i / 1444;
            int rem = i - ch * 1444;
            int y = rem / 38;
            int xx = rem - y * 38;
            int gh = th0 + y - 3;
            int gw = tw0 + xx - 3;
            float val = 0.f;
            if ((unsigned)gh < 128u && (unsigned)gw < 128u)
                val = pooled[ch * NP + (((b << 4) + tsrc) << 14) + (gh << 7) + gw];
            sm[ch * (38 * 39) + y * 39 + xx] = val;
        }
        __syncthreads();

        const float* wdz = wgt + dz * 49;
#pragma unroll
        for (int ch = 0; ch < 2; ++ch) {
#pragma unroll
            for (int dy = 0; dy < 7; ++dy) {
                const float* rp = &sm[ch * (38 * 39) + (ty + dy) * 39 + txg];
                float row[10];
#pragma unroll
                for (int k = 0; k < 10; ++k) row[k] = rp[k];
                const float* wr = wdz + ch * 343 + dy * 7;
#pragma unroll
                for (int dx = 0; dx < 7; ++dx) {
                    float wv = wr[dx];
                    acc0 = fmaf(wv, row[dx + 0], acc0);
                    acc1 = fmaf(wv, row[dx + 1], acc1);
                    acc2 = fmaf(wv, row[dx + 2], acc2);
                    acc3 = fmaf(wv, row[dx + 3], acc3);
                }
            }
        }
    }

    float4 o;
    o.x = 1.f / (1.f + expf(-acc0));
    o.y = 1.f / (1.f + expf(-acc1));
    o.z = 1.f / (1.f + expf(-acc2));
    o.w = 1.f / (1.f + expf(-acc3));
    int oi = (((b << 4) + t) << 14) + ((th0 + ty) << 7) + (tw0 + txg);
    *(float4*)(attn + oi) = o; // 16B aligned: txg multiple of 4
}

// ---------------- Kernel 3: out = attn (broadcast over C) * x ----------------
__global__ __launch_bounds__(256) void mul_kernel(const float* __restrict__ x,
                                                  const float* __restrict__ attn,
                                                  float* __restrict__ out) {
    int j = blockIdx.x * 256 + threadIdx.x; // float4 index, [0, 2^23)
    const float4* x4 = (const float4*)x;
    const float4* a4 = (const float4*)attn;
    float4 xv = x4[j];
    float4 av = a4[((j >> 22) << 16) | (j & 65535)]; // strip c, keep (b, t*hw)
    float4 o;
    o.x = xv.x * av.x;
    o.y = xv.y * av.y;
    o.z = xv.z * av.z;
    o.w = xv.w * av.w;
    ((float4*)out)[j] = o;
}

extern "C" void kernel_launch(void* const* d_in, const int* in_sizes, int n_in,
                              void* d_out, int out_size, void* d_ws, size_t ws_size,
                              hipStream_t stream) {
    const float* x = (const float*)d_in[0];
    const float* w = (const float*)d_in[1];
    float* out = (float*)d_out;
    float* ws = (float*)d_ws;

    float* pmax = ws;           // NP floats
    float* pavg = ws + NP;      // NP floats (must follow pmax: conv indexes ch*NP)
    float* attn = ws + 2 * NP;  // NP floats

    pool_kernel<<<NP / 4 / 256, 256, 0, stream>>>(x, pmax, pavg);
    conv_kernel<<<2 * 16 * 4 * 4, 256, 0, stream>>>(pmax, w, attn);
    mul_kernel<<<(1 << 23) / 256, 256, 0, stream>>>(x, attn, out);
}

// Round 3
// 273.338 us; speedup vs baseline: 1.0272x; 1.0272x over previous
//
#include <hip/hip_runtime.h>
#include <math.h>

// Problem: x (B=2, C=64, T=16, H=128, W=128) fp32; w (1,2,7,7,7) fp32.
// out = sigmoid(conv3d(concat[max_c(x), mean_c(x)], w, pad=3)) * x
//
// R2 structure: 2 kernels (R1 fused plan, compile fix for nontemporal store).
//   K1 pool:      x (128 MiB) -> pmax|pavg (4 MiB)
//   K2 conv+mul:  conv3d over pooled (LDS-tiled, per-plane), sigmoid kept in
//                 registers (each thread owns the exact 4 pixels it needs for
//                 the broadcast multiply), then out = attn * x with
//                 non-temporal stores so x stays L3-resident for its 2nd read.

#define NP (2 * 16 * 128 * 128) // 524288 pooled points per channel

typedef float vfloat4 __attribute__((ext_vector_type(4))); // native vector: ok for nontemporal builtins

// ---------------- Kernel 1: channel max + mean pool (float4) ----------------
__global__ __launch_bounds__(256) void pool_kernel(const float* __restrict__ x,
                                                   float* __restrict__ pmax,
                                                   float* __restrict__ pavg) {
    int j = blockIdx.x * 256 + threadIdx.x; // float4 index in pooled space, [0, 131072)
    int b = j >> 16;                        // 65536 float4 per batch in pooled space
    int rest = j & 65535;
    const float4* x4 = (const float4*)x;
    int base = (b << 22) | rest;            // float4 index into x for c=0

    float4 v = x4[base];
    float4 vmax = v;
    float4 vsum = v;
#pragma unroll 8
    for (int c = 1; c < 64; ++c) {
        float4 u = x4[base + (c << 16)];
        vmax.x = fmaxf(vmax.x, u.x);
        vmax.y = fmaxf(vmax.y, u.y);
        vmax.z = fmaxf(vmax.z, u.z);
        vmax.w = fmaxf(vmax.w, u.w);
        vsum.x += u.x; vsum.y += u.y; vsum.z += u.z; vsum.w += u.w;
    }
    const float s = 1.0f / 64.0f;
    float4 vavg; vavg.x = vsum.x * s; vavg.y = vsum.y * s; vavg.z = vsum.z * s; vavg.w = vsum.w * s;
    ((float4*)pmax)[j] = vmax;
    ((float4*)pavg)[j] = vavg;
}

// -------- Kernel 2: 7x7x7 conv (2ch) + sigmoid + broadcast multiply ---------
// Block = 256 threads handles one (b, t) and a 32x32 (h,w) tile.
// LDS stages one dz-plane of the 2-channel pooled halo: 2 x 38 x 38 (stride 39).
// Each thread computes attn for its own 4 consecutive-w pixels, keeps them in
// registers, then streams all 64 channels of x through them.
__global__ __launch_bounds__(256) void conv_mul_kernel(const float* __restrict__ pooled, // pmax | pavg contiguous
                                                       const float* __restrict__ wgt,    // (1,2,7,7,7)
                                                       const float* __restrict__ x,
                                                       float* __restrict__ out) {
    __shared__ float sm[2 * 38 * 39]; // 11856 B

    int bid = blockIdx.x;
    int tw0 = (bid & 3) << 5;
    int th0 = ((bid >> 2) & 3) << 5;
    int t = (bid >> 4) & 15;
    int b = bid >> 8;

    int tid = threadIdx.x;
    int ty = tid >> 3;         // 0..31 output row within tile
    int txg = (tid & 7) << 2;  // 0,4,...,28 output col group (4 consecutive w)

    float acc0 = 0.f, acc1 = 0.f, acc2 = 0.f, acc3 = 0.f;

    for (int dz = 0; dz < 7; ++dz) {
        int tsrc = t + dz - 3;
        if (tsrc < 0 || tsrc >= 16) continue; // block-uniform: barriers stay uniform

        __syncthreads(); // protect LDS from previous plane's readers
        for (int i = tid; i < 2 * 38 * 38; i += 256) {
            int ch = i / 1444;
            int rem = i - ch * 1444;
            int y = rem / 38;
            int xx = rem - y * 38;
            int gh = th0 + y - 3;
            int gw = tw0 + xx - 3;
            float val = 0.f;
            if ((unsigned)gh < 128u && (unsigned)gw < 128u)
                val = pooled[ch * NP + (((b << 4) + tsrc) << 14) + (gh << 7) + gw];
            sm[ch * (38 * 39) + y * 39 + xx] = val;
        }
        __syncthreads();

        const float* wdz = wgt + dz * 49;
#pragma unroll
        for (int ch = 0; ch < 2; ++ch) {
#pragma unroll
            for (int dy = 0; dy < 7; ++dy) {
                const float* rp = &sm[ch * (38 * 39) + (ty + dy) * 39 + txg];
                float row[10];
#pragma unroll
                for (int k = 0; k < 10; ++k) row[k] = rp[k];
                const float* wr = wdz + ch * 343 + dy * 7;
#pragma unroll
                for (int dx = 0; dx < 7; ++dx) {
                    float wv = wr[dx];
                    acc0 = fmaf(wv, row[dx + 0], acc0);
                    acc1 = fmaf(wv, row[dx + 1], acc1);
                    acc2 = fmaf(wv, row[dx + 2], acc2);
                    acc3 = fmaf(wv, row[dx + 3], acc3);
                }
            }
        }
    }

    float a0 = 1.f / (1.f + expf(-acc0));
    float a1 = 1.f / (1.f + expf(-acc1));
    float a2 = 1.f / (1.f + expf(-acc2));
    float a3 = 1.f / (1.f + expf(-acc3));

    // Phase 2: out[b, c, t, gh, gw..gw+3] = attn * x, for all 64 channels.
    // float4 index: b*2^22 + c*2^16 + t*2^12 + gh*2^5 + gw/4
    int base4 = (b << 22) + (t << 12) + ((th0 + ty) << 5) + ((tw0 + txg) >> 2);
    const vfloat4* x4 = (const vfloat4*)x;
    vfloat4* o4 = (vfloat4*)out;
    vfloat4 av = {a0, a1, a2, a3};
#pragma unroll 4
    for (int c = 0; c < 64; ++c) {
        int idx = base4 + (c << 16);
        vfloat4 xv = x4[idx];
        __builtin_nontemporal_store(xv * av, &o4[idx]); // don't evict x from L3
    }
}

extern "C" void kernel_launch(void* const* d_in, const int* in_sizes, int n_in,
                              void* d_out, int out_size, void* d_ws, size_t ws_size,
                              hipStream_t stream) {
    const float* x = (const float*)d_in[0];
    const float* w = (const float*)d_in[1];
    float* out = (float*)d_out;
    float* ws = (float*)d_ws;

    float* pmax = ws;       // NP floats
    float* pavg = ws + NP;  // NP floats (must follow pmax: conv indexes ch*NP)

    pool_kernel<<<NP / 4 / 256, 256, 0, stream>>>(x, pmax, pavg);
    conv_mul_kernel<<<2 * 16 * 4 * 4, 256, 0, stream>>>(pmax, w, x, out);
}

// Round 4
// 269.390 us; speedup vs baseline: 1.0423x; 1.0147x over previous
//
#include <hip/hip_runtime.h>
#include <math.h>

// Problem: x (B=2, C=64, T=16, H=128, W=128) fp32; w (1,2,7,7,7) fp32.
// out = sigmoid(conv3d(concat[max_c(x), mean_c(x)], w, pad=3)) * x
//
// R3 structure: 2 kernels (fused conv+sigmoid+mul), plus micro-opts:
//   - prefetch 8 channels of x into VGPRs before conv phase (latency overlap)
//   - per-block channel-start stagger in the streaming phase
//   - unroll-8 streaming loop
//   K1 pool:      x (128 MiB) -> pmax|pavg (4 MiB)      [HBM-bound, ~22 us]
//   K2 conv+mul:  conv3d over pooled (LDS per-plane), attn kept in registers,
//                 out = attn * x with non-temporal stores (keep x L3-resident).

#define NP (2 * 16 * 128 * 128) // 524288 pooled points per channel

typedef float vfloat4 __attribute__((ext_vector_type(4))); // native vec: ok for nontemporal builtins

// ---------------- Kernel 1: channel max + mean pool (float4) ----------------
__global__ __launch_bounds__(256) void pool_kernel(const float* __restrict__ x,
                                                   float* __restrict__ pmax,
                                                   float* __restrict__ pavg) {
    int j = blockIdx.x * 256 + threadIdx.x; // float4 index in pooled space, [0, 131072)
    int b = j >> 16;                        // 65536 float4 per batch in pooled space
    int rest = j & 65535;
    const float4* x4 = (const float4*)x;
    int base = (b << 22) | rest;            // float4 index into x for c=0

    float4 v = x4[base];
    float4 vmax = v;
    float4 vsum = v;
#pragma unroll 8
    for (int c = 1; c < 64; ++c) {
        float4 u = x4[base + (c << 16)];
        vmax.x = fmaxf(vmax.x, u.x);
        vmax.y = fmaxf(vmax.y, u.y);
        vmax.z = fmaxf(vmax.z, u.z);
        vmax.w = fmaxf(vmax.w, u.w);
        vsum.x += u.x; vsum.y += u.y; vsum.z += u.z; vsum.w += u.w;
    }
    const float s = 1.0f / 64.0f;
    float4 vavg; vavg.x = vsum.x * s; vavg.y = vsum.y * s; vavg.z = vsum.z * s; vavg.w = vsum.w * s;
    ((float4*)pmax)[j] = vmax;
    ((float4*)pavg)[j] = vavg;
}

// -------- Kernel 2: 7x7x7 conv (2ch) + sigmoid + broadcast multiply ---------
// Block = 256 threads handles one (b, t) and a 32x32 (h,w) tile.
// LDS stages one dz-plane of the 2-channel pooled halo: 2 x 38 x 38 (stride 39).
// Each thread computes attn for its own 4 consecutive-w pixels, keeps them in
// registers, then streams all 64 channels of x through them.
__global__ __launch_bounds__(256) void conv_mul_kernel(const float* __restrict__ pooled, // pmax | pavg contiguous
                                                       const float* __restrict__ wgt,    // (1,2,7,7,7)
                                                       const float* __restrict__ x,
                                                       float* __restrict__ out) {
    __shared__ float sm[2 * 38 * 39]; // 11856 B

    int bid = blockIdx.x;
    int tw0 = (bid & 3) << 5;
    int th0 = ((bid >> 2) & 3) << 5;
    int t = (bid >> 4) & 15;
    int b = bid >> 8;

    int tid = threadIdx.x;
    int ty = tid >> 3;         // 0..31 output row within tile
    int txg = (tid & 7) << 2;  // 0,4,...,28 output col group (4 consecutive w)

    // Phase-2 addressing, computed early so prefetch loads can issue now.
    // float4 index: b*2^22 + c*2^16 + t*2^12 + gh*2^5 + gw/4
    int base4 = (b << 22) + (t << 12) + ((th0 + ty) << 5) + ((tw0 + txg) >> 2);
    int cs = bid & 63; // per-block channel stagger
    const vfloat4* x4 = (const vfloat4*)x;
    vfloat4* o4 = (vfloat4*)out;

    // Prefetch first 8 staggered channels of x: loads fly during the conv
    // phase; data parks in VGPRs until the streaming phase.
    vfloat4 pre[8];
#pragma unroll
    for (int k = 0; k < 8; ++k)
        pre[k] = x4[base4 + (((cs + k) & 63) << 16)];

    float acc0 = 0.f, acc1 = 0.f, acc2 = 0.f, acc3 = 0.f;

    for (int dz = 0; dz < 7; ++dz) {
        int tsrc = t + dz - 3;
        if (tsrc < 0 || tsrc >= 16) continue; // block-uniform: barriers stay uniform

        __syncthreads(); // protect LDS from previous plane's readers
        for (int i = tid; i < 2 * 38 * 38; i += 256) {
            int ch = i / 1444;
            int rem = i - ch * 1444;
            int y = rem / 38;
            int xx = rem - y * 38;
            int gh = th0 + y - 3;
            int gw = tw0 + xx - 3;
            float val = 0.f;
            if ((unsigned)gh < 128u && (unsigned)gw < 128u)
                val = pooled[ch * NP + (((b << 4) + tsrc) << 14) + (gh << 7) + gw];
            sm[ch * (38 * 39) + y * 39 + xx] = val;
        }
        __syncthreads();

        const float* wdz = wgt + dz * 49;
#pragma unroll
        for (int ch = 0; ch < 2; ++ch) {
#pragma unroll
            for (int dy = 0; dy < 7; ++dy) {
                const float* rp = &sm[ch * (38 * 39) + (ty + dy) * 39 + txg];
                float row[10];
#pragma unroll
                for (int k = 0; k < 10; ++k) row[k] = rp[k];
                const float* wr = wdz + ch * 343 + dy * 7;
#pragma unroll
                for (int dx = 0; dx < 7; ++dx) {
                    float wv = wr[dx];
                    acc0 = fmaf(wv, row[dx + 0], acc0);
                    acc1 = fmaf(wv, row[dx + 1], acc1);
                    acc2 = fmaf(wv, row[dx + 2], acc2);
                    acc3 = fmaf(wv, row[dx + 3], acc3);
                }
            }
        }
    }

    vfloat4 av;
    av.x = 1.f / (1.f + __expf(-acc0));
    av.y = 1.f / (1.f + __expf(-acc1));
    av.z = 1.f / (1.f + __expf(-acc2));
    av.w = 1.f / (1.f + __expf(-acc3));

    // Phase 2: out[b, c, t, gh, gw..gw+3] = attn * x, for all 64 channels,
    // staggered start channel per block; non-temporal stores keep x in L3.
#pragma unroll
    for (int k = 0; k < 8; ++k) {
        int idx = base4 + (((cs + k) & 63) << 16);
        __builtin_nontemporal_store(pre[k] * av, &o4[idx]);
    }
#pragma unroll 8
    for (int k = 8; k < 64; ++k) {
        int idx = base4 + (((cs + k) & 63) << 16);
        vfloat4 xv = x4[idx];
        __builtin_nontemporal_store(xv * av, &o4[idx]);
    }
}

extern "C" void kernel_launch(void* const* d_in, const int* in_sizes, int n_in,
                              void* d_out, int out_size, void* d_ws, size_t ws_size,
                              hipStream_t stream) {
    const float* x = (const float*)d_in[0];
    const float* w = (const float*)d_in[1];
    float* out = (float*)d_out;
    float* ws = (float*)d_ws;

    float* pmax = ws;       // NP floats
    float* pavg = ws + NP;  // NP floats (must follow pmax: conv indexes ch*NP)

    pool_kernel<<<NP / 4 / 256, 256, 0, stream>>>(x, pmax, pavg);
    conv_mul_kernel<<<2 * 16 * 4 * 4, 256, 0, stream>>>(pmax, w, x, out);
}